// Round 6
// baseline (2725.638 us; speedup 1.0000x reference)
//
#include <hip/hip_runtime.h>
#include <hip/hip_bf16.h>

typedef __attribute__((ext_vector_type(4))) float f32x4;
typedef __attribute__((ext_vector_type(8))) short bf16x8;

#define M_DIM 8192
#define N_DIM 4096
#define K_DIM 4096
#define NH 8
#define R_DIM 16
#define HQ 128          // NH * R_DIM

__device__ __forceinline__ unsigned short f2bf(float f) {
  union { float f; unsigned int u; } v; v.f = f;
  unsigned int r = v.u + 0x7fffu + ((v.u >> 16) & 1u);  // RNE
  return (unsigned short)(r >> 16);
}

__device__ __forceinline__ void gll16(const void* gptr, void* lptr) {
  __builtin_amdgcn_global_load_lds(
      (const __attribute__((address_space(1))) void*)gptr,
      (__attribute__((address_space(3))) void*)lptr, 16, 0, 0);
}

#define FENCE() asm volatile("" ::: "memory")
#define BAR() do { FENCE(); __builtin_amdgcn_s_barrier(); FENCE(); } while (0)

// ---------------- Kernel 1: cast x (f32) -> bf16 ----------------
__global__ void k_cast_bf16(const float* __restrict__ in,
                            unsigned short* __restrict__ out, int n4) {
  int i = blockIdx.x * 256 + threadIdx.x;
  if (i >= n4) return;
  float4 v = reinterpret_cast<const float4*>(in)[i];
  ushort4 o;
  o.x = f2bf(v.x); o.y = f2bf(v.y); o.z = f2bf(v.z); o.w = f2bf(v.w);
  reinterpret_cast<ushort4*>(out)[i] = o;
}

// ---------------- Kernel 2a: HA_T[d][h*16+q] = bf16( s[h]*sum_r H[h][q][r]*A[h][r][d] )
__global__ void k_ha_t(const float* __restrict__ A, const float* __restrict__ H,
                       const float* __restrict__ s, unsigned short* __restrict__ HA_T) {
  const int d = blockIdx.x * 256 + threadIdx.x;
  const int h = blockIdx.y;
  const float* Ah = A + (size_t)h * R_DIM * K_DIM;
  const float* Hh = H + h * R_DIM * R_DIM;
  const float sv = s[h];
  float acc[R_DIM];
  #pragma unroll
  for (int q = 0; q < R_DIM; ++q) acc[q] = 0.f;
  #pragma unroll
  for (int r = 0; r < R_DIM; ++r) {
    float a = Ah[(size_t)r * K_DIM + d];
    #pragma unroll
    for (int q = 0; q < R_DIM; ++q) acc[q] += Hh[q * R_DIM + r] * a;
  }
  unsigned short o[R_DIM];
  #pragma unroll
  for (int q = 0; q < R_DIM; ++q) o[q] = f2bf(acc[q] * sv);
  *reinterpret_cast<uint4*>(&HA_T[(size_t)d * HQ + h * R_DIM]) = *reinterpret_cast<uint4*>(o);
  *reinterpret_cast<uint4*>(&HA_T[(size_t)d * HQ + h * R_DIM + 8]) = *reinterpret_cast<uint4*>(o + 8);
}

// ---------------- Kernel 2b: Bc[o][h*16+q] = bf16( B[h][o][q] ) ----------------
__global__ void k_bcat(const float* __restrict__ Bm, unsigned short* __restrict__ Bc) {
  const int t = threadIdx.x;
  const int ol = t >> 4, q = t & 15;
  const int o = blockIdx.x * 16 + ol;
  #pragma unroll
  for (int h = 0; h < NH; ++h)
    Bc[(size_t)o * HQ + h * R_DIM + q] = f2bf(Bm[((size_t)h * N_DIM + o) * R_DIM + q]);
}

// ---------------- Kernel 3: Weff = bf16(W + Bc @ HA_T^T), K=128 MFMA GEMM ----------------
__global__ __launch_bounds__(256)
void k_weff_mfma(const unsigned short* __restrict__ Ab,   // Bc [4096][128]
                 const unsigned short* __restrict__ Bb,   // HA_T [4096][128]
                 const float* __restrict__ W,
                 unsigned short* __restrict__ Weff) {
  constexpr int WK = HQ;  // 128
  __shared__ unsigned short As[128 * 32];
  __shared__ unsigned short Bs[128 * 32];

  const int t = threadIdx.x;
  const int lane = t & 63;
  const int wave = t >> 6;
  const int wr = wave >> 1, wc = wave & 1;
  const int brow = blockIdx.y * 128;
  const int bcol = blockIdx.x * 128;

  const int r0 = t >> 2, ch = t & 3;
  const size_t a_off0 = (size_t)(brow + r0) * WK + ch * 8;
  const size_t a_off1 = (size_t)(brow + r0 + 64) * WK + ch * 8;
  const size_t b_off0 = (size_t)(bcol + r0) * WK + ch * 8;
  const size_t b_off1 = (size_t)(bcol + r0 + 64) * WK + ch * 8;
  unsigned short* as_d0 = As + t * 8;
  unsigned short* as_d1 = As + (t + 256) * 8;
  unsigned short* bs_d0 = Bs + t * 8;
  unsigned short* bs_d1 = Bs + (t + 256) * 8;

  const int fr = lane & 15;
  const int kk = (lane >> 4) * 8;

  f32x4 acc[4][4] = {};

  for (int k0 = 0; k0 < WK; k0 += 32) {
    gll16(Ab + a_off0 + k0, as_d0);
    gll16(Ab + a_off1 + k0, as_d1);
    gll16(Bb + b_off0 + k0, bs_d0);
    gll16(Bb + b_off1 + k0, bs_d1);
    __syncthreads();

    bf16x8 af[4], bfr[4];
    #pragma unroll
    for (int m = 0; m < 4; ++m)
      af[m] = *reinterpret_cast<const bf16x8*>(&As[(wr * 64 + m * 16 + fr) * 32 + kk]);
    #pragma unroll
    for (int n = 0; n < 4; ++n)
      bfr[n] = *reinterpret_cast<const bf16x8*>(&Bs[(wc * 64 + n * 16 + fr) * 32 + kk]);

    #pragma unroll
    for (int m = 0; m < 4; ++m)
      #pragma unroll
      for (int n = 0; n < 4; ++n)
        acc[m][n] = __builtin_amdgcn_mfma_f32_16x16x32_bf16(af[m], bfr[n], acc[m][n], 0, 0, 0);

    __syncthreads();
  }

  const int crow0 = brow + wr * 64 + (lane >> 4) * 4;
  const int ccol0 = bcol + wc * 64 + fr;
  #pragma unroll
  for (int m = 0; m < 4; ++m)
    #pragma unroll
    for (int n = 0; n < 4; ++n) {
      const int col = ccol0 + n * 16;
      #pragma unroll
      for (int r = 0; r < 4; ++r) {
        const size_t idx = (size_t)(crow0 + m * 16 + r) * N_DIM + col;
        Weff[idx] = f2bf(acc[m][n][r] + W[idx]);
      }
    }
}

// ---------------- Kernel 4: 256x256-tile 8-phase GEMM, BK=32, 64 KB LDS ----------------
// Same slot schedule / ledger as the proven BK=64 version, halved K-step so that
// LDS = 64 KB -> 2 blocks/CU co-resident (all 512 blocks resident at once).
// Slots per operand: 4 x [128][32] bf16; tile T half h -> slot (T&1)*2+h.
// Phase: {LOAD; STAGE (1 gll16); MFMA quad (8); [vmcnt(3) at p3/p7]; BAR}.
// vmcnt(3)@p3 confirms prev-p5..p7 + p0; @p7 confirms p1..p4.  Stage/read slots
// disjoint per phase; every restage >=1 barrier after that slot's last read.
// Swizzle: linear LDS dest + inverse-swizzled global source; involution
// chunk' = chunk ^ ((row>>1)&3) on 16B chunks within each 64 B row.
__global__ __launch_bounds__(512, 4)
void k_gemm256(const unsigned short* __restrict__ A,
               const unsigned short* __restrict__ Bw,
               const float* __restrict__ bias,
               float* __restrict__ C) {
  __shared__ unsigned short As[4][128][32];  // 32 KB
  __shared__ unsigned short Bs[4][128][32];  // 32 KB
  constexpr int SLOT_E = 128 * 32;           // 4096 elem = 8 KB per slot

  const int t    = threadIdx.x;
  const int lane = t & 63;
  const int wave = t >> 6;
  const int wr   = wave >> 2;      // 0..1
  const int wc   = wave & 3;       // 0..3
  const int fr   = lane & 15;
  const int kq   = lane >> 4;      // 0..3

  const int bid = blockIdx.x;
  const int swz = (bid & 7) * 64 + (bid >> 3);
  const int brow = (swz >> 4) * 256;
  const int bcol = (swz & 15) * 256;

  const unsigned short* Ag = A  + (size_t)brow * K_DIM;
  const unsigned short* Bg = Bw + (size_t)bcol * K_DIM;

  // staging: 512 chunks of 16B per half-tile, chunk i = t: row = t>>2, LDS chunk t&3;
  // global source chunk = (t&3) ^ ((row>>1)&3)  (inverse of the read swizzle).
  const int r_s = t >> 2;                              // 0..127
  const int c_e = (((t & 3) ^ ((r_s >> 1) & 3)) * 8);  // element offset in row

  unsigned short* as0 = &As[0][0][0];
  unsigned short* bs0 = &Bs[0][0][0];
  const char* lds_a = (const char*)as0;
  const char* lds_b = (const char*)bs0;

  // read addressing: row = (64*wr|32*wc) + m|n*16 + fr; row bits1-2 == fr bits1-2.
  const int sx   = (fr >> 1) & 3;
  const int colx = ((kq ^ sx) * 16);          // byte offset within 64 B row
  const int arow = wr * 64 + fr;
  const int browl = wc * 32 + fr;

#define STAGE(DST, GBASE, T_, H_) \
    gll16((GBASE) + (size_t)((H_) * 128 + r_s) * K_DIM + (T_) * 32 + c_e, (DST) + t * 8)

#define LOAD_A(SLOT) do { \
    _Pragma("unroll") for (int m = 0; m < 4; ++m) \
      ar[m] = *(const bf16x8*)(lds_a + (SLOT) * 8192 + (arow + m * 16) * 64 + colx); \
  } while (0)

#define LOAD_B(SLOT, BR) do { \
    _Pragma("unroll") for (int n = 0; n < 2; ++n) \
      BR[n] = *(const bf16x8*)(lds_b + (SLOT) * 8192 + (browl + n * 16) * 64 + colx); \
  } while (0)

#define MFMA_QUAD(MH, NHX, BR) do { \
    __builtin_amdgcn_s_setprio(1); \
    _Pragma("unroll") for (int m = 0; m < 4; ++m) \
    _Pragma("unroll") for (int n = 0; n < 2; ++n) \
      acc[MH][NHX][m][n] = __builtin_amdgcn_mfma_f32_16x16x32_bf16(ar[m], BR[n], acc[MH][NHX][m][n], 0, 0, 0); \
    __builtin_amdgcn_s_setprio(0); \
  } while (0)

  bf16x8 ar[4];
  bf16x8 b0r[2];
  bf16x8 b1r[2];
  f32x4 acc[2][2][4][2] = {};

  // ---- prologue: tile0 fully + tile1 (A0,B0,B1)
  STAGE(as0 + 0 * SLOT_E, Ag, 0, 0);
  STAGE(bs0 + 0 * SLOT_E, Bg, 0, 0);
  STAGE(bs0 + 1 * SLOT_E, Bg, 0, 1);
  STAGE(as0 + 1 * SLOT_E, Ag, 0, 1);
  STAGE(as0 + 2 * SLOT_E, Ag, 1, 0);
  STAGE(bs0 + 2 * SLOT_E, Bg, 1, 0);
  STAGE(bs0 + 3 * SLOT_E, Bg, 1, 1);
  asm volatile("s_waitcnt vmcnt(3)" ::: "memory");   // tile0's 4 halves resident
  __builtin_amdgcn_s_barrier();
  FENCE();

  #pragma unroll 1
  for (int it = 0; it < 63; ++it) {
    const int T = 2 * it;
    // p0
    LOAD_A(0); LOAD_B(0, b0r);
    STAGE(as0 + 3 * SLOT_E, Ag, T + 1, 1);
    MFMA_QUAD(0, 0, b0r); BAR();
    // p1
    LOAD_B(1, b1r);
    STAGE(as0 + 0 * SLOT_E, Ag, T + 2, 0);
    MFMA_QUAD(0, 1, b1r); BAR();
    // p2
    LOAD_A(1);
    STAGE(bs0 + 0 * SLOT_E, Bg, T + 2, 0);
    MFMA_QUAD(1, 0, b0r); BAR();
    // p3
    STAGE(bs0 + 1 * SLOT_E, Bg, T + 2, 1);
    MFMA_QUAD(1, 1, b1r);
    asm volatile("s_waitcnt vmcnt(3)" ::: "memory");
    BAR();
    // p4
    LOAD_A(2); LOAD_B(2, b0r);
    STAGE(as0 + 1 * SLOT_E, Ag, T + 2, 1);
    MFMA_QUAD(0, 0, b0r); BAR();
    // p5
    LOAD_B(3, b1r);
    STAGE(as0 + 2 * SLOT_E, Ag, T + 3, 0);
    MFMA_QUAD(0, 1, b1r); BAR();
    // p6
    LOAD_A(3);
    STAGE(bs0 + 2 * SLOT_E, Bg, T + 3, 0);
    MFMA_QUAD(1, 0, b0r); BAR();
    // p7
    STAGE(bs0 + 3 * SLOT_E, Bg, T + 3, 1);
    MFMA_QUAD(1, 1, b1r);
    asm volatile("s_waitcnt vmcnt(3)" ::: "memory");
    BAR();
  }

  // ---- epilogue: tiles 126 (slots 0,1) and 127 (slots 2,3); A1(127) missing.
  STAGE(as0 + 3 * SLOT_E, Ag, 127, 1);
  asm volatile("s_waitcnt vmcnt(0)" ::: "memory");
  __builtin_amdgcn_s_barrier();
  FENCE();
  LOAD_A(0); LOAD_B(0, b0r); MFMA_QUAD(0, 0, b0r);
  LOAD_B(1, b1r);            MFMA_QUAD(0, 1, b1r);
  LOAD_A(1);                 MFMA_QUAD(1, 0, b0r);
                             MFMA_QUAD(1, 1, b1r);
  LOAD_A(2); LOAD_B(2, b0r); MFMA_QUAD(0, 0, b0r);
  LOAD_B(3, b1r);            MFMA_QUAD(0, 1, b1r);
  LOAD_A(3);                 MFMA_QUAD(1, 0, b0r);
                             MFMA_QUAD(1, 1, b1r);

#undef STAGE
#undef LOAD_A
#undef LOAD_B
#undef MFMA_QUAD

  // ---- C write: C/D layout col=lane&15, row=4*(lane>>4)+reg (m89-verified)
  const int crow = brow + wr * 64 + kq * 4;
  const int ccol = bcol + wc * 32 + fr;
  #pragma unroll
  for (int mh = 0; mh < 2; ++mh)
  #pragma unroll
  for (int nh = 0; nh < 2; ++nh)
  #pragma unroll
  for (int m = 0; m < 4; ++m)
  #pragma unroll
  for (int n = 0; n < 2; ++n) {
    const int col = ccol + nh * 128 + n * 16;
    const float bv = bias[col];
    #pragma unroll
    for (int r = 0; r < 4; ++r)
      C[(size_t)(crow + mh * 128 + m * 16 + r) * N_DIM + col] = acc[mh][nh][m][n][r] + bv;
  }
}

// ---------------- launch ----------------
extern "C" void kernel_launch(void* const* d_in, const int* in_sizes, int n_in,
                              void* d_out, int out_size, void* d_ws, size_t ws_size,
                              hipStream_t stream) {
  const float* x  = (const float*)d_in[0];
  const float* W  = (const float*)d_in[1];
  const float* bv = (const float*)d_in[2];
  const float* Am = (const float*)d_in[3];
  const float* Hm = (const float*)d_in[4];
  const float* Bm = (const float*)d_in[5];
  const float* sv = (const float*)d_in[6];
  float* out = (float*)d_out;

  char* ws = (char*)d_ws;
  unsigned short* xbf  = (unsigned short*)ws;                                 // 64 MB
  unsigned short* weff = (unsigned short*)(ws + (size_t)M_DIM * K_DIM * 2);   // 32 MB
  unsigned short* hat  = (unsigned short*)(ws + (size_t)(M_DIM + N_DIM) * K_DIM * 2);          // 1 MB
  unsigned short* bc   = (unsigned short*)(ws + (size_t)(M_DIM + N_DIM) * K_DIM * 2 + (size_t)N_DIM * HQ * 2); // 1 MB

  k_cast_bf16<<<(M_DIM * K_DIM / 4 + 255) / 256, 256, 0, stream>>>(x, xbf, M_DIM * K_DIM / 4);
  k_ha_t<<<dim3(K_DIM / 256, NH), 256, 0, stream>>>(Am, Hm, sv, hat);
  k_bcat<<<N_DIM / 16, 256, 0, stream>>>(Bm, bc);
  k_weff_mfma<<<dim3(N_DIM / 128, N_DIM / 128), 256, 0, stream>>>(bc, hat, W, weff);
  k_gemm256<<<dim3(512), 512, 0, stream>>>(xbf, weff, bv, out);
}

// Round 7
// 385.493 us; speedup vs baseline: 7.0705x; 7.0705x over previous
//
#include <hip/hip_runtime.h>
#include <hip/hip_bf16.h>

typedef __attribute__((ext_vector_type(4))) float f32x4;
typedef __attribute__((ext_vector_type(8))) short bf16x8;

#define M_DIM 8192
#define N_DIM 4096
#define K_DIM 4096
#define NH 8
#define R_DIM 16
#define HQ 128          // NH * R_DIM

__device__ __forceinline__ unsigned short f2bf(float f) {
  union { float f; unsigned int u; } v; v.f = f;
  unsigned int r = v.u + 0x7fffu + ((v.u >> 16) & 1u);  // RNE
  return (unsigned short)(r >> 16);
}

__device__ __forceinline__ void gll16(const void* gptr, void* lptr) {
  __builtin_amdgcn_global_load_lds(
      (const __attribute__((address_space(1))) void*)gptr,
      (__attribute__((address_space(3))) void*)lptr, 16, 0, 0);
}

#define FENCE() asm volatile("" ::: "memory")
#define BAR() do { FENCE(); __builtin_amdgcn_s_barrier(); FENCE(); } while (0)
#define VMC(N) asm volatile("s_waitcnt vmcnt(" #N ")" ::: "memory")

// ---------------- Kernel 1: cast x (f32) -> bf16 ----------------
__global__ void k_cast_bf16(const float* __restrict__ in,
                            unsigned short* __restrict__ out, int n4) {
  int i = blockIdx.x * 256 + threadIdx.x;
  if (i >= n4) return;
  float4 v = reinterpret_cast<const float4*>(in)[i];
  ushort4 o;
  o.x = f2bf(v.x); o.y = f2bf(v.y); o.z = f2bf(v.z); o.w = f2bf(v.w);
  reinterpret_cast<ushort4*>(out)[i] = o;
}

// ---------------- Kernel 2a: HA_T[d][h*16+q] = bf16( s[h]*sum_r H[h][q][r]*A[h][r][d] )
__global__ void k_ha_t(const float* __restrict__ A, const float* __restrict__ H,
                       const float* __restrict__ s, unsigned short* __restrict__ HA_T) {
  const int d = blockIdx.x * 256 + threadIdx.x;
  const int h = blockIdx.y;
  const float* Ah = A + (size_t)h * R_DIM * K_DIM;
  const float* Hh = H + h * R_DIM * R_DIM;
  const float sv = s[h];
  float acc[R_DIM];
  #pragma unroll
  for (int q = 0; q < R_DIM; ++q) acc[q] = 0.f;
  #pragma unroll
  for (int r = 0; r < R_DIM; ++r) {
    float a = Ah[(size_t)r * K_DIM + d];
    #pragma unroll
    for (int q = 0; q < R_DIM; ++q) acc[q] += Hh[q * R_DIM + r] * a;
  }
  unsigned short o[R_DIM];
  #pragma unroll
  for (int q = 0; q < R_DIM; ++q) o[q] = f2bf(acc[q] * sv);
  *reinterpret_cast<uint4*>(&HA_T[(size_t)d * HQ + h * R_DIM]) = *reinterpret_cast<uint4*>(o);
  *reinterpret_cast<uint4*>(&HA_T[(size_t)d * HQ + h * R_DIM + 8]) = *reinterpret_cast<uint4*>(o + 8);
}

// ---------------- Kernel 2b: Bc[o][h*16+q] = bf16( B[h][o][q] ) ----------------
__global__ void k_bcat(const float* __restrict__ Bm, unsigned short* __restrict__ Bc) {
  const int t = threadIdx.x;
  const int ol = t >> 4, q = t & 15;
  const int o = blockIdx.x * 16 + ol;
  #pragma unroll
  for (int h = 0; h < NH; ++h)
    Bc[(size_t)o * HQ + h * R_DIM + q] = f2bf(Bm[((size_t)h * N_DIM + o) * R_DIM + q]);
}

// ---------------- Kernel 3: Weff = bf16(W + Bc @ HA_T^T), K=128 MFMA GEMM ----------------
__global__ __launch_bounds__(256)
void k_weff_mfma(const unsigned short* __restrict__ Ab,   // Bc [4096][128]
                 const unsigned short* __restrict__ Bb,   // HA_T [4096][128]
                 const float* __restrict__ W,
                 unsigned short* __restrict__ Weff) {
  constexpr int WK = HQ;  // 128
  __shared__ unsigned short As[128 * 32];
  __shared__ unsigned short Bs[128 * 32];

  const int t = threadIdx.x;
  const int lane = t & 63;
  const int wave = t >> 6;
  const int wr = wave >> 1, wc = wave & 1;
  const int brow = blockIdx.y * 128;
  const int bcol = blockIdx.x * 128;

  const int r0 = t >> 2, ch = t & 3;
  const size_t a_off0 = (size_t)(brow + r0) * WK + ch * 8;
  const size_t a_off1 = (size_t)(brow + r0 + 64) * WK + ch * 8;
  const size_t b_off0 = (size_t)(bcol + r0) * WK + ch * 8;
  const size_t b_off1 = (size_t)(bcol + r0 + 64) * WK + ch * 8;
  unsigned short* as_d0 = As + t * 8;
  unsigned short* as_d1 = As + (t + 256) * 8;
  unsigned short* bs_d0 = Bs + t * 8;
  unsigned short* bs_d1 = Bs + (t + 256) * 8;

  const int fr = lane & 15;
  const int kk = (lane >> 4) * 8;

  f32x4 acc[4][4] = {};

  for (int k0 = 0; k0 < WK; k0 += 32) {
    gll16(Ab + a_off0 + k0, as_d0);
    gll16(Ab + a_off1 + k0, as_d1);
    gll16(Bb + b_off0 + k0, bs_d0);
    gll16(Bb + b_off1 + k0, bs_d1);
    __syncthreads();

    bf16x8 af[4], bfr[4];
    #pragma unroll
    for (int m = 0; m < 4; ++m)
      af[m] = *reinterpret_cast<const bf16x8*>(&As[(wr * 64 + m * 16 + fr) * 32 + kk]);
    #pragma unroll
    for (int n = 0; n < 4; ++n)
      bfr[n] = *reinterpret_cast<const bf16x8*>(&Bs[(wc * 64 + n * 16 + fr) * 32 + kk]);

    #pragma unroll
    for (int m = 0; m < 4; ++m)
      #pragma unroll
      for (int n = 0; n < 4; ++n)
        acc[m][n] = __builtin_amdgcn_mfma_f32_16x16x32_bf16(af[m], bfr[n], acc[m][n], 0, 0, 0);

    __syncthreads();
  }

  const int crow0 = brow + wr * 64 + (lane >> 4) * 4;
  const int ccol0 = bcol + wc * 64 + fr;
  #pragma unroll
  for (int m = 0; m < 4; ++m)
    #pragma unroll
    for (int n = 0; n < 4; ++n) {
      const int col = ccol0 + n * 16;
      #pragma unroll
      for (int r = 0; r < 4; ++r) {
        const size_t idx = (size_t)(crow0 + m * 16 + r) * N_DIM + col;
        Weff[idx] = f2bf(acc[m][n][r] + W[idx]);
      }
    }
}

// ---------------- Kernel 4: 256x256-tile 8-phase GEMM, BK=64, read-ahead frags ------
// R5 skeleton (slots, stages, swizzle, vmcnt points) + fragment loads issued ONE
// phase early so ds_read drain overlaps the previous MFMA quad (compiler-derived
// counted lgkmcnt; raw s_barrier does NOT force lgkm(0), so reads stay in flight
// across barriers).  Reg sets: arA/arB (A-halves ping-pong), bE/bO (B ping-pong).
// Phase p: {issue reads for q(p+1); STAGE; MFMA q(p); [VMC(4)+post-wait reads at
// p3/p7]; BAR}.  Ledger (verified): every read's slot confirmed by the preceding
// vmcnt; every restage >=1 barrier after that slot's reads drained.
__global__ __launch_bounds__(512, 2)
void k_gemm256(const unsigned short* __restrict__ A,
               const unsigned short* __restrict__ Bw,
               const float* __restrict__ bias,
               float* __restrict__ C) {
  __shared__ unsigned short As[4][128][64];  // 64 KB
  __shared__ unsigned short Bs[4][128][64];  // 64 KB
  constexpr int SLOT_E = 128 * 64;

  const int t    = threadIdx.x;
  const int lane = t & 63;
  const int wave = t >> 6;
  const int wr   = wave >> 2;
  const int wc   = wave & 3;
  const int fr   = lane & 15;
  const int kq   = lane >> 4;

  const int bid = blockIdx.x;
  const int swz = (bid & 7) * 64 + (bid >> 3);
  const int brow = (swz >> 4) * 256;
  const int bcol = (swz & 15) * 256;

  const unsigned short* Ag = A  + (size_t)brow * K_DIM;
  const unsigned short* Bg = Bw + (size_t)bcol * K_DIM;

  const int i0 = t, i1 = 512 + t;
  const int r_s0 = i0 >> 3, r_s1 = i1 >> 3;
  const int c_e0 = (((i0 & 7) * 16) ^ ((r_s0 & 7) << 4)) >> 1;
  const int c_e1 = (((i1 & 7) * 16) ^ ((r_s1 & 7) << 4)) >> 1;

  unsigned short* as0 = &As[0][0][0];
  unsigned short* bs0 = &Bs[0][0][0];
  const char* lds_a = (const char*)as0;
  const char* lds_b = (const char*)bs0;

  const int arow = wr * 64 + fr;
  const int browl = wc * 32 + fr;
  const int axr = (fr & 7) << 4;

#define STAGE(DST, GBASE, T_, H_) do { \
    gll16((GBASE) + (size_t)((H_) * 128 + r_s0) * K_DIM + (T_) * 64 + c_e0, (DST) + i0 * 8); \
    gll16((GBASE) + (size_t)((H_) * 128 + r_s1) * K_DIM + (T_) * 64 + c_e1, (DST) + i1 * 8); \
  } while (0)

#define RA(AR, SLOT) do { \
    _Pragma("unroll") for (int m = 0; m < 4; ++m) \
    _Pragma("unroll") for (int ks = 0; ks < 2; ++ks) \
      AR[m][ks] = *(const bf16x8*)(lds_a + (SLOT) * 16384 + (arow + m * 16) * 128 + ((kq * 16 + ks * 64) ^ axr)); \
  } while (0)

#define RB(BR, SLOT) do { \
    _Pragma("unroll") for (int n = 0; n < 2; ++n) \
    _Pragma("unroll") for (int ks = 0; ks < 2; ++ks) \
      BR[n][ks] = *(const bf16x8*)(lds_b + (SLOT) * 16384 + (browl + n * 16) * 128 + ((kq * 16 + ks * 64) ^ axr)); \
  } while (0)

#define QUAD(MH, NHX, AR, BR) do { \
    __builtin_amdgcn_s_setprio(1); \
    _Pragma("unroll") for (int m = 0; m < 4; ++m) \
    _Pragma("unroll") for (int n = 0; n < 2; ++n) \
    _Pragma("unroll") for (int ks = 0; ks < 2; ++ks) \
      acc[MH][NHX][m][n] = __builtin_amdgcn_mfma_f32_16x16x32_bf16(AR[m][ks], BR[n][ks], acc[MH][NHX][m][n], 0, 0, 0); \
    __builtin_amdgcn_s_setprio(0); \
  } while (0)

  bf16x8 arA[4][2], arB[4][2];   // A-half fragment ping-pong
  bf16x8 bE[2][2],  bO[2][2];    // B-half fragment ping-pong
  f32x4 acc[2][2][4][2] = {};

  // ---- prologue: tile0 fully + tile1 (A0,B0,B1); preload q0 fragments.
  STAGE(as0 + 0 * SLOT_E, Ag, 0, 0);   // #1 A0
  STAGE(bs0 + 0 * SLOT_E, Bg, 0, 0);   // #2 B0
  STAGE(bs0 + 1 * SLOT_E, Bg, 0, 1);   // #3 B1
  STAGE(as0 + 1 * SLOT_E, Ag, 0, 1);   // #4 A1
  STAGE(as0 + 2 * SLOT_E, Ag, 1, 0);   // #5 A2
  STAGE(bs0 + 2 * SLOT_E, Bg, 1, 0);   // #6 B2
  STAGE(bs0 + 3 * SLOT_E, Bg, 1, 1);   // #7 B3
  VMC(6);                               // confirms #1..#4 (A0,B0,B1,A1)
  BAR();
  RA(arA, 0); RB(bE, 0);                // q0 fragments in flight / draining

  #pragma unroll 1
  for (int it = 0; it < 31; ++it) {
    const int T = 2 * it;
    // p0: MFMA q(0,0)[arA,bE]; issue bO<-B1(T); stage A3<-A1(T+1)
    RB(bO, 1);
    STAGE(as0 + 3 * SLOT_E, Ag, T + 1, 1);
    QUAD(0, 0, arA, bE);
    BAR();
    // p1: MFMA q(0,1)[arA,bO]; issue arB<-A1(T); stage A0<-A0(T+2)
    RA(arB, 1);
    STAGE(as0 + 0 * SLOT_E, Ag, T + 2, 0);
    QUAD(0, 1, arA, bO);
    BAR();
    // p2: MFMA q(1,0)[arB,bE]; no reads; stage B0<-B0(T+2)
    STAGE(bs0 + 0 * SLOT_E, Bg, T + 2, 0);
    QUAD(1, 0, arB, bE);
    BAR();
    // p3: MFMA q(1,1)[arB,bO]; stage B1<-B1(T+2); vmcnt; then reads arA<-A0(T+1), bE<-B0(T+1)
    STAGE(bs0 + 1 * SLOT_E, Bg, T + 2, 1);
    QUAD(1, 1, arB, bO);
    VMC(4);
    RA(arA, 2); RB(bE, 2);
    BAR();
    // p4: MFMA q(0,0)[arA,bE]; issue bO<-B1(T+1); stage A1<-A1(T+2)
    RB(bO, 3);
    STAGE(as0 + 1 * SLOT_E, Ag, T + 2, 1);
    QUAD(0, 0, arA, bE);
    BAR();
    // p5: MFMA q(0,1)[arA,bO]; issue arB<-A1(T+1); stage A2<-A0(T+3)
    RA(arB, 3);
    STAGE(as0 + 2 * SLOT_E, Ag, T + 3, 0);
    QUAD(0, 1, arA, bO);
    BAR();
    // p6: MFMA q(1,0)[arB,bE]; no reads; stage B2<-B0(T+3)
    STAGE(bs0 + 2 * SLOT_E, Bg, T + 3, 0);
    QUAD(1, 0, arB, bE);
    BAR();
    // p7: MFMA q(1,1)[arB,bO]; stage B3<-B1(T+3); vmcnt; reads arA<-A0(T+2), bE<-B0(T+2)
    STAGE(bs0 + 3 * SLOT_E, Bg, T + 3, 1);
    QUAD(1, 1, arB, bO);
    VMC(4);
    RA(arA, 0); RB(bE, 0);
    BAR();
  }

  // ---- epilogue: tiles 62 (slots A0/B0, A1/B1) and 63 (A2/B2, A3/B3)
  STAGE(as0 + 3 * SLOT_E, Ag, 63, 1);   // A3 <- A1(63) (stale A1(61) fully read)
  VMC(0);
  BAR();
  RB(bO, 1);             QUAD(0, 0, arA, bE);
  RA(arB, 1);            QUAD(0, 1, arA, bO);
                         QUAD(1, 0, arB, bE);
  RA(arA, 2); RB(bE, 2); QUAD(1, 1, arB, bO);
  RB(bO, 3);             QUAD(0, 0, arA, bE);
  RA(arB, 3);            QUAD(0, 1, arA, bO);
                         QUAD(1, 0, arB, bE);
                         QUAD(1, 1, arB, bO);

#undef STAGE
#undef RA
#undef RB
#undef QUAD

  // ---- C write: C/D layout col=lane&15, row=4*(lane>>4)+reg (m89-verified)
  const int crow = brow + wr * 64 + kq * 4;
  const int ccol = bcol + wc * 32 + fr;
  #pragma unroll
  for (int mh = 0; mh < 2; ++mh)
  #pragma unroll
  for (int nh = 0; nh < 2; ++nh)
  #pragma unroll
  for (int m = 0; m < 4; ++m)
  #pragma unroll
  for (int n = 0; n < 2; ++n) {
    const int col = ccol + nh * 128 + n * 16;
    const float bv = bias[col];
    #pragma unroll
    for (int r = 0; r < 4; ++r)
      C[(size_t)(crow + mh * 128 + m * 16 + r) * N_DIM + col] = acc[mh][nh][m][n][r] + bv;
  }
}

// ---------------- launch ----------------
extern "C" void kernel_launch(void* const* d_in, const int* in_sizes, int n_in,
                              void* d_out, int out_size, void* d_ws, size_t ws_size,
                              hipStream_t stream) {
  const float* x  = (const float*)d_in[0];
  const float* W  = (const float*)d_in[1];
  const float* bv = (const float*)d_in[2];
  const float* Am = (const float*)d_in[3];
  const float* Hm = (const float*)d_in[4];
  const float* Bm = (const float*)d_in[5];
  const float* sv = (const float*)d_in[6];
  float* out = (float*)d_out;

  char* ws = (char*)d_ws;
  unsigned short* xbf  = (unsigned short*)ws;                                 // 64 MB
  unsigned short* weff = (unsigned short*)(ws + (size_t)M_DIM * K_DIM * 2);   // 32 MB
  unsigned short* hat  = (unsigned short*)(ws + (size_t)(M_DIM + N_DIM) * K_DIM * 2);          // 1 MB
  unsigned short* bc   = (unsigned short*)(ws + (size_t)(M_DIM + N_DIM) * K_DIM * 2 + (size_t)N_DIM * HQ * 2); // 1 MB

  k_cast_bf16<<<(M_DIM * K_DIM / 4 + 255) / 256, 256, 0, stream>>>(x, xbf, M_DIM * K_DIM / 4);
  k_ha_t<<<dim3(K_DIM / 256, NH), 256, 0, stream>>>(Am, Hm, sv, hat);
  k_bcat<<<N_DIM / 16, 256, 0, stream>>>(Bm, bc);
  k_weff_mfma<<<dim3(N_DIM / 128, N_DIM / 128), 256, 0, stream>>>(bc, hat, W, weff);
  k_gemm256<<<dim3(512), 512, 0, stream>>>(xbf, weff, bv, out);
}

// Round 8
// 318.788 us; speedup vs baseline: 8.5500x; 1.2092x over previous
//
#include <hip/hip_runtime.h>
#include <hip/hip_bf16.h>

typedef __attribute__((ext_vector_type(4))) float f32x4;
typedef __attribute__((ext_vector_type(8))) short bf16x8;

#define M_DIM 8192
#define N_DIM 4096
#define K_DIM 4096
#define NH 8
#define R_DIM 16
#define HQ 128          // NH * R_DIM

__device__ __forceinline__ unsigned short f2bf(float f) {
  union { float f; unsigned int u; } v; v.f = f;
  unsigned int r = v.u + 0x7fffu + ((v.u >> 16) & 1u);  // RNE
  return (unsigned short)(r >> 16);
}

__device__ __forceinline__ void gll16(const void* gptr, void* lptr) {
  __builtin_amdgcn_global_load_lds(
      (const __attribute__((address_space(1))) void*)gptr,
      (__attribute__((address_space(3))) void*)lptr, 16, 0, 0);
}

#define FENCE() asm volatile("" ::: "memory")
#define BAR() do { FENCE(); __builtin_amdgcn_s_barrier(); FENCE(); } while (0)
#define VMC0() asm volatile("s_waitcnt vmcnt(0)" ::: "memory")

// ---------------- Kernel 1: cast x (f32) -> bf16 ----------------
__global__ void k_cast_bf16(const float* __restrict__ in,
                            unsigned short* __restrict__ out, int n4) {
  int i = blockIdx.x * 256 + threadIdx.x;
  if (i >= n4) return;
  float4 v = reinterpret_cast<const float4*>(in)[i];
  ushort4 o;
  o.x = f2bf(v.x); o.y = f2bf(v.y); o.z = f2bf(v.z); o.w = f2bf(v.w);
  reinterpret_cast<ushort4*>(out)[i] = o;
}

// ---------------- Kernel 2a: HA_T[d][h*16+q] = bf16( s[h]*sum_r H[h][q][r]*A[h][r][d] )
__global__ void k_ha_t(const float* __restrict__ A, const float* __restrict__ H,
                       const float* __restrict__ s, unsigned short* __restrict__ HA_T) {
  const int d = blockIdx.x * 256 + threadIdx.x;
  const int h = blockIdx.y;
  const float* Ah = A + (size_t)h * R_DIM * K_DIM;
  const float* Hh = H + h * R_DIM * R_DIM;
  const float sv = s[h];
  float acc[R_DIM];
  #pragma unroll
  for (int q = 0; q < R_DIM; ++q) acc[q] = 0.f;
  #pragma unroll
  for (int r = 0; r < R_DIM; ++r) {
    float a = Ah[(size_t)r * K_DIM + d];
    #pragma unroll
    for (int q = 0; q < R_DIM; ++q) acc[q] += Hh[q * R_DIM + r] * a;
  }
  unsigned short o[R_DIM];
  #pragma unroll
  for (int q = 0; q < R_DIM; ++q) o[q] = f2bf(acc[q] * sv);
  *reinterpret_cast<uint4*>(&HA_T[(size_t)d * HQ + h * R_DIM]) = *reinterpret_cast<uint4*>(o);
  *reinterpret_cast<uint4*>(&HA_T[(size_t)d * HQ + h * R_DIM + 8]) = *reinterpret_cast<uint4*>(o + 8);
}

// ---------------- Kernel 2b: Bc[o][h*16+q] = bf16( B[h][o][q] ) ----------------
__global__ void k_bcat(const float* __restrict__ Bm, unsigned short* __restrict__ Bc) {
  const int t = threadIdx.x;
  const int ol = t >> 4, q = t & 15;
  const int o = blockIdx.x * 16 + ol;
  #pragma unroll
  for (int h = 0; h < NH; ++h)
    Bc[(size_t)o * HQ + h * R_DIM + q] = f2bf(Bm[((size_t)h * N_DIM + o) * R_DIM + q]);
}

// ---------------- Kernel 3: Weff = bf16(W + Bc @ HA_T^T), K=128 MFMA GEMM ----------------
__global__ __launch_bounds__(256)
void k_weff_mfma(const unsigned short* __restrict__ Ab,   // Bc [4096][128]
                 const unsigned short* __restrict__ Bb,   // HA_T [4096][128]
                 const float* __restrict__ W,
                 unsigned short* __restrict__ Weff) {
  constexpr int WK = HQ;  // 128
  __shared__ unsigned short As[128 * 32];
  __shared__ unsigned short Bs[128 * 32];

  const int t = threadIdx.x;
  const int lane = t & 63;
  const int wave = t >> 6;
  const int wr = wave >> 1, wc = wave & 1;
  const int brow = blockIdx.y * 128;
  const int bcol = blockIdx.x * 128;

  const int r0 = t >> 2, ch = t & 3;
  const size_t a_off0 = (size_t)(brow + r0) * WK + ch * 8;
  const size_t a_off1 = (size_t)(brow + r0 + 64) * WK + ch * 8;
  const size_t b_off0 = (size_t)(bcol + r0) * WK + ch * 8;
  const size_t b_off1 = (size_t)(bcol + r0 + 64) * WK + ch * 8;
  unsigned short* as_d0 = As + t * 8;
  unsigned short* as_d1 = As + (t + 256) * 8;
  unsigned short* bs_d0 = Bs + t * 8;
  unsigned short* bs_d1 = Bs + (t + 256) * 8;

  const int fr = lane & 15;
  const int kk = (lane >> 4) * 8;

  f32x4 acc[4][4] = {};

  for (int k0 = 0; k0 < WK; k0 += 32) {
    gll16(Ab + a_off0 + k0, as_d0);
    gll16(Ab + a_off1 + k0, as_d1);
    gll16(Bb + b_off0 + k0, bs_d0);
    gll16(Bb + b_off1 + k0, bs_d1);
    __syncthreads();

    bf16x8 af[4], bfr[4];
    #pragma unroll
    for (int m = 0; m < 4; ++m)
      af[m] = *reinterpret_cast<const bf16x8*>(&As[(wr * 64 + m * 16 + fr) * 32 + kk]);
    #pragma unroll
    for (int n = 0; n < 4; ++n)
      bfr[n] = *reinterpret_cast<const bf16x8*>(&Bs[(wc * 64 + n * 16 + fr) * 32 + kk]);

    #pragma unroll
    for (int m = 0; m < 4; ++m)
      #pragma unroll
      for (int n = 0; n < 4; ++n)
        acc[m][n] = __builtin_amdgcn_mfma_f32_16x16x32_bf16(af[m], bfr[n], acc[m][n], 0, 0, 0);

    __syncthreads();
  }

  const int crow0 = brow + wr * 64 + (lane >> 4) * 4;
  const int ccol0 = bcol + wc * 64 + fr;
  #pragma unroll
  for (int m = 0; m < 4; ++m)
    #pragma unroll
    for (int n = 0; n < 4; ++n) {
      const int col = ccol0 + n * 16;
      #pragma unroll
      for (int r = 0; r < 4; ++r) {
        const size_t idx = (size_t)(crow0 + m * 16 + r) * N_DIM + col;
        Weff[idx] = f2bf(acc[m][n][r] + W[idx]);
      }
    }
}

// ---------------- Kernel 4: 256x256-tile GEMM, barrier-free K-tile interior ----------
// Iter i computes K-tile i from parity slots par=i&1 ({2par,2par+1} of A and B);
// stages tile min(i+1,63) into par^1 slots (disjoint from ALL intra-iter reads);
// 4 quadrant chunks (reads+16 MFMA) with NO internal sync — compiler schedules the
// whole tile region; waves de-phase so LDS reads overlap other waves' MFMAs.
// Even/odd waves traverse quadrants in rotated order (two static code paths).
// End of iter: VMC0 (own stages, issued a full iter earlier) + BAR globalizes
// per-wave vmcnt before any wave reads the new tile.  Safety: read-issue order
// precedes barrier in program order -> LDS queue serves reads before any
// post-barrier stage write; stages/read slots disjoint within an iter.
__global__ __launch_bounds__(512, 2)
void k_gemm256(const unsigned short* __restrict__ A,
               const unsigned short* __restrict__ Bw,
               const float* __restrict__ bias,
               float* __restrict__ C) {
  __shared__ unsigned short As[4][128][64];  // 64 KB
  __shared__ unsigned short Bs[4][128][64];  // 64 KB
  constexpr int SLOT_E = 128 * 64;

  const int t    = threadIdx.x;
  const int lane = t & 63;
  const int wave = t >> 6;
  const int wr   = wave >> 2;
  const int wc   = wave & 3;
  const int fr   = lane & 15;
  const int kq   = lane >> 4;

  const int bid = blockIdx.x;
  const int swz = (bid & 7) * 64 + (bid >> 3);
  const int brow = (swz >> 4) * 256;
  const int bcol = (swz & 15) * 256;

  const unsigned short* Ag = A  + (size_t)brow * K_DIM;
  const unsigned short* Bg = Bw + (size_t)bcol * K_DIM;

  const int i0 = t, i1 = 512 + t;
  const int r_s0 = i0 >> 3, r_s1 = i1 >> 3;
  const int c_e0 = (((i0 & 7) * 16) ^ ((r_s0 & 7) << 4)) >> 1;
  const int c_e1 = (((i1 & 7) * 16) ^ ((r_s1 & 7) << 4)) >> 1;

  unsigned short* as0 = &As[0][0][0];
  unsigned short* bs0 = &Bs[0][0][0];
  const char* lds_a = (const char*)as0;
  const char* lds_b = (const char*)bs0;

  const int arow = wr * 64 + fr;
  const int browl = wc * 32 + fr;
  const int axr = (fr & 7) << 4;

#define STAGE(DST, GBASE, T_, H_) do { \
    gll16((GBASE) + (size_t)((H_) * 128 + r_s0) * K_DIM + (T_) * 64 + c_e0, (DST) + i0 * 8); \
    gll16((GBASE) + (size_t)((H_) * 128 + r_s1) * K_DIM + (T_) * 64 + c_e1, (DST) + i1 * 8); \
  } while (0)

// stage all 4 half-tiles of tile T_ into parity-P slots
#define STAGE_TILE(T_, P_) do { \
    STAGE(as0 + (2*(P_) + 0) * SLOT_E, Ag, T_, 0); \
    STAGE(as0 + (2*(P_) + 1) * SLOT_E, Ag, T_, 1); \
    STAGE(bs0 + (2*(P_) + 0) * SLOT_E, Bg, T_, 0); \
    STAGE(bs0 + (2*(P_) + 1) * SLOT_E, Bg, T_, 1); \
  } while (0)

#define RA(AR, SLOT) do { \
    _Pragma("unroll") for (int m = 0; m < 4; ++m) \
    _Pragma("unroll") for (int ks = 0; ks < 2; ++ks) \
      AR[m][ks] = *(const bf16x8*)(lds_a + (SLOT) * 16384 + (arow + m * 16) * 128 + ((kq * 16 + ks * 64) ^ axr)); \
  } while (0)

#define RB(BR, SLOT) do { \
    _Pragma("unroll") for (int n = 0; n < 2; ++n) \
    _Pragma("unroll") for (int ks = 0; ks < 2; ++ks) \
      BR[n][ks] = *(const bf16x8*)(lds_b + (SLOT) * 16384 + (browl + n * 16) * 128 + ((kq * 16 + ks * 64) ^ axr)); \
  } while (0)

#define QUAD(MH, NHX, AR, BR) do { \
    __builtin_amdgcn_s_setprio(1); \
    _Pragma("unroll") for (int m = 0; m < 4; ++m) \
    _Pragma("unroll") for (int n = 0; n < 2; ++n) \
    _Pragma("unroll") for (int ks = 0; ks < 2; ++ks) \
      acc[MH][NHX][m][n] = __builtin_amdgcn_mfma_f32_16x16x32_bf16(AR[m][ks], BR[n][ks], acc[MH][NHX][m][n], 0, 0, 0); \
    __builtin_amdgcn_s_setprio(0); \
  } while (0)

// one K-tile body, parity P_ static.  EVEN wave order: Q00,Q01,Q10,Q11.
#define BODY_EVEN(T_, TN_, P_) do { \
    STAGE_TILE(TN_, 1 - (P_)); \
    RA(arE, 2*(P_) + 0); RB(bE, 2*(P_) + 0); \
    QUAD(0, 0, arE, bE); \
    RB(bO, 2*(P_) + 1); \
    QUAD(0, 1, arE, bO); \
    RA(arO, 2*(P_) + 1); \
    QUAD(1, 0, arO, bE); \
    QUAD(1, 1, arO, bO); \
    VMC0(); \
    BAR(); \
  } while (0)

// ODD wave order: Q10,Q11,Q00,Q01 (reads A-half1 first)
#define BODY_ODD(T_, TN_, P_) do { \
    STAGE_TILE(TN_, 1 - (P_)); \
    RA(arO, 2*(P_) + 1); RB(bE, 2*(P_) + 0); \
    QUAD(1, 0, arO, bE); \
    RB(bO, 2*(P_) + 1); \
    QUAD(1, 1, arO, bO); \
    RA(arE, 2*(P_) + 0); \
    QUAD(0, 0, arE, bE); \
    QUAD(0, 1, arE, bO); \
    VMC0(); \
    BAR(); \
  } while (0)

  bf16x8 arE[4][2], arO[4][2];   // A-half0 / A-half1 fragments
  bf16x8 bE[2][2],  bO[2][2];    // B-half0 / B-half1 fragments
  f32x4 acc[2][2][4][2] = {};

  // ---- prologue: stage tile0 into parity-0 slots; wait; barrier.
  STAGE_TILE(0, 0);
  VMC0();
  BAR();

  if ((wave & 1) == 0) {
    #pragma unroll 1
    for (int it = 0; it < 64; it += 2) {
      const int tn1 = it + 1;
      const int tn2 = (it + 2 < 64) ? (it + 2) : 63;
      BODY_EVEN(it,     tn1, 0);
      BODY_EVEN(it + 1, tn2, 1);
    }
  } else {
    #pragma unroll 1
    for (int it = 0; it < 64; it += 2) {
      const int tn1 = it + 1;
      const int tn2 = (it + 2 < 64) ? (it + 2) : 63;
      BODY_ODD(it,     tn1, 0);
      BODY_ODD(it + 1, tn2, 1);
    }
  }

#undef STAGE
#undef STAGE_TILE
#undef RA
#undef RB
#undef QUAD
#undef BODY_EVEN
#undef BODY_ODD

  // ---- C write: C/D layout col=lane&15, row=4*(lane>>4)+reg (m89-verified)
  const int crow = brow + wr * 64 + kq * 4;
  const int ccol = bcol + wc * 32 + fr;
  #pragma unroll
  for (int mh = 0; mh < 2; ++mh)
  #pragma unroll
  for (int nh = 0; nh < 2; ++nh)
  #pragma unroll
  for (int m = 0; m < 4; ++m)
  #pragma unroll
  for (int n = 0; n < 2; ++n) {
    const int col = ccol + nh * 128 + n * 16;
    const float bv = bias[col];
    #pragma unroll
    for (int r = 0; r < 4; ++r)
      C[(size_t)(crow + mh * 128 + m * 16 + r) * N_DIM + col] = acc[mh][nh][m][n][r] + bv;
  }
}

// ---------------- launch ----------------
extern "C" void kernel_launch(void* const* d_in, const int* in_sizes, int n_in,
                              void* d_out, int out_size, void* d_ws, size_t ws_size,
                              hipStream_t stream) {
  const float* x  = (const float*)d_in[0];
  const float* W  = (const float*)d_in[1];
  const float* bv = (const float*)d_in[2];
  const float* Am = (const float*)d_in[3];
  const float* Hm = (const float*)d_in[4];
  const float* Bm = (const float*)d_in[5];
  const float* sv = (const float*)d_in[6];
  float* out = (float*)d_out;

  char* ws = (char*)d_ws;
  unsigned short* xbf  = (unsigned short*)ws;                                 // 64 MB
  unsigned short* weff = (unsigned short*)(ws + (size_t)M_DIM * K_DIM * 2);   // 32 MB
  unsigned short* hat  = (unsigned short*)(ws + (size_t)(M_DIM + N_DIM) * K_DIM * 2);          // 1 MB
  unsigned short* bc   = (unsigned short*)(ws + (size_t)(M_DIM + N_DIM) * K_DIM * 2 + (size_t)N_DIM * HQ * 2); // 1 MB

  k_cast_bf16<<<(M_DIM * K_DIM / 4 + 255) / 256, 256, 0, stream>>>(x, xbf, M_DIM * K_DIM / 4);
  k_ha_t<<<dim3(K_DIM / 256, NH), 256, 0, stream>>>(Am, Hm, sv, hat);
  k_bcat<<<N_DIM / 16, 256, 0, stream>>>(Bm, bc);
  k_weff_mfma<<<dim3(N_DIM / 128, N_DIM / 128), 256, 0, stream>>>(bc, hat, W, weff);
  k_gemm256<<<dim3(512), 512, 0, stream>>>(xbf, weff, bv, out);
}